// Round 3
// baseline (197.405 us; speedup 1.0000x reference)
//
#include <hip/hip_runtime.h>
#include <hip/hip_fp16.h>
#include <stdint.h>

typedef _Float16 f16;
typedef __attribute__((ext_vector_type(8))) _Float16 f16x8;
typedef __attribute__((ext_vector_type(4))) _Float16 f16x4;
typedef __attribute__((ext_vector_type(4))) float f32x4;

#define SEQ 2048
#define DIM 1024
#define NBATCH 2
#define MTOT 4096  // NBATCH*SEQ

__global__ void fill_kernel(float* p, float v, int n){
  int i = blockIdx.x * 256 + threadIdx.x;
  if (i < n) p[i] = v;
}

// x (4M floats) -> fp16, 4 elems/thread
__global__ void cvt_x_kernel(const float* __restrict__ src, f16* __restrict__ dst){
  int i = blockIdx.x * 256 + threadIdx.x;
  float4 v = ((const float4*)src)[i];
  ((f16x4*)dst)[i] = (f16x4){(f16)v.x, (f16)v.y, (f16)v.z, (f16)v.w};
}

// Wq,Wk,Wv -> Wcat (3072x1024 fp16), Wo -> Wo16. 1024 blocks per tensor.
__global__ void cvt_w_kernel(const float* __restrict__ Wq, const float* __restrict__ Wk,
                             const float* __restrict__ Wv, const float* __restrict__ Wo,
                             f16* __restrict__ Wcat, f16* __restrict__ Wo16){
  int b = blockIdx.x;
  int t = b >> 10;
  int i = (b & 1023) * 256 + threadIdx.x;
  const float* src = t == 0 ? Wq : t == 1 ? Wk : t == 2 ? Wv : Wo;
  f16* dst = (t == 3) ? Wo16 : Wcat + (size_t)t * DIM * DIM;
  float4 v = ((const float4*)src)[i];
  ((f16x4*)dst)[i] = (f16x4){(f16)v.x, (f16)v.y, (f16)v.z, (f16)v.w};
}

#define GLOAD16(SRC, DST) __builtin_amdgcn_global_load_lds( \
    (__attribute__((address_space(1))) void*)(SRC), \
    (__attribute__((address_space(3))) void*)(DST), 16, 0, 0)

// ---------------------------------------------------------------------------
// 256x256 8-phase GEMM (T2 swizzle + T3/T4 counted vmcnt + T5 setprio).
// C = A @ B^T. A:(M,K) fp16 row-major, B:(N,K) fp16 row-major. BK=64.
// 512 threads = 8 waves, wave grid 2M x 4N, INTERLEAVED 16-row/col stripes:
//   wave (wr,wc): C rows = m*32 + wr*16 + 0..15 (m=0..7), cols = n*64 + wc*16 + 0..15 (n=0..3)
// => A-frag half = m>>2, B-frag half = n>>1 (phase-local LDS halves).
// LDS: As/Bs [dbuf][half][128*64] f16 = 128 KiB total. Stage = global_load_lds
// w=16, linear dest, pre-swizzled source colblk ^= (row&7); reads apply same XOR.
// Phase schedule per K-tile t (dbuf d=t&1, stages -> e=d^1 for K-tile t+1):
//   p0: read A-mh0(8) B-nh0(4); stage Ah0',Bh0' (4 ld); W1=vmcnt(4); bar; lgkm0; 16 MFMA; bar
//   p1: read B-nh1(4);          stage Bh1' (2 ld);                   bar; lgkm0; 16 MFMA; bar
//   p2: read A-mh1(8);          stage Ah1' (2 ld);                   bar; lgkm0; 16 MFMA; bar
//   p3:                         W2=vmcnt(4);                                     16 MFMA; bar
// FIFO proof: W2(t-1) newest-4 = {Bh1(t),Ah1(t)} => Ah0/Bh0(t) landed for p0;
//             W1(t) newest-4 = pair(t+1) => Bh1(t),Ah1(t) landed for p1/p2.
// MODE 0: fp32 out (+bias0 if set) -> Cf
// MODE 4: fused qkv: col<2048 -> Ch(q|k, ldc=2048), col>=2048 -> vT[b][d][t]
// ---------------------------------------------------------------------------
template<int MODE>
__global__ __launch_bounds__(512, 2)
void gemm8p(const f16* __restrict__ A, const f16* __restrict__ B,
            int K, int lda, int ldb, long bsA, long bsB, long bsC,
            float* __restrict__ Cf, f16* __restrict__ Ch, f16* __restrict__ vT,
            const float* __restrict__ bias0, const float* __restrict__ bias1,
            const float* __restrict__ bias2, int ldc)
{
  __shared__ __align__(16) f16 As[2][2][8192];
  __shared__ __align__(16) f16 Bs[2][2][8192];
  const int tid  = threadIdx.x;
  const int lane = tid & 63;
  const int wid  = tid >> 6;
  const int wr = wid >> 2, wc = wid & 3;
  const int bm = blockIdx.x, bn = blockIdx.y, bz = blockIdx.z;

  // staging: thread covers (row s_r + 64*ld, 8 f16 at swizzled colblk), dest linear tid*16B
  const int s_r  = tid >> 3;
  const int s_cb = (tid & 7) ^ (s_r & 7);
  const f16* Abase = A + (long)bz * bsA + (long)(bm * 256) * lda + s_cb * 8;
  const f16* Bbase = B + (long)bz * bsB + (long)(bn * 256) * ldb + s_cb * 8;

#define STAGE_A(D,H,TT) do{ \
    GLOAD16(Abase + (long)((H)*128 +      s_r) * lda + (TT)*64, &As[D][H][tid*8]); \
    GLOAD16(Abase + (long)((H)*128 + 64 + s_r) * lda + (TT)*64, &As[D][H][4096 + tid*8]); \
  }while(0)
#define STAGE_B(D,H,TT) do{ \
    GLOAD16(Bbase + (long)((H)*128 +      s_r) * ldb + (TT)*64, &Bs[D][H][tid*8]); \
    GLOAD16(Bbase + (long)((H)*128 + 64 + s_r) * ldb + (TT)*64, &Bs[D][H][4096 + tid*8]); \
  }while(0)

  // frag-read addressing (swizzled): row-in-half, colblk^(row&7)
  const int l15 = lane & 15, l7 = lane & 7, lhi = lane >> 4;
  const int arow = wr * 16 + l15;              // + (m&3)*32
  const int brow = wc * 16 + l15;              // + (n&1)*64
  const int cbo0 = (((0) + lhi) ^ l7) * 8;     // kk=0
  const int cbo1 = (((4) + lhi) ^ l7) * 8;     // kk=1

  f32x4 acc[8][4] = {};
  f16x8 af[4][2], bf[4][2];

  const int NT = K >> 6;

  // prologue: K-tile 0 fully into dbuf 0
  STAGE_A(0,0,0); STAGE_A(0,1,0); STAGE_B(0,0,0); STAGE_B(0,1,0);
  asm volatile("s_waitcnt vmcnt(0)" ::: "memory");
  __builtin_amdgcn_s_barrier();

  for (int t = 0; t < NT; ++t){
    const int d = t & 1, e = d ^ 1;
    const bool st = (t + 1 < NT);
    // ---------------- phase 0
#pragma unroll
    for (int m = 0; m < 4; m++){
      af[m][0] = *(const f16x8*)&As[d][0][(m*32 + arow)*64 + cbo0];
      af[m][1] = *(const f16x8*)&As[d][0][(m*32 + arow)*64 + cbo1];
    }
#pragma unroll
    for (int n = 0; n < 2; n++){
      bf[n][0] = *(const f16x8*)&Bs[d][0][(n*64 + brow)*64 + cbo0];
      bf[n][1] = *(const f16x8*)&Bs[d][0][(n*64 + brow)*64 + cbo1];
    }
    if (st){
      STAGE_A(e,0,t+1); STAGE_B(e,0,t+1);
      asm volatile("s_waitcnt vmcnt(4)" ::: "memory");
    } else {
      asm volatile("s_waitcnt vmcnt(0)" ::: "memory");
    }
    __builtin_amdgcn_s_barrier();
    asm volatile("s_waitcnt lgkmcnt(0)" ::: "memory");
    __builtin_amdgcn_sched_barrier(0);
    __builtin_amdgcn_s_setprio(1);
#pragma unroll
    for (int m = 0; m < 4; m++)
#pragma unroll
      for (int n = 0; n < 2; n++){
        acc[m][n] = __builtin_amdgcn_mfma_f32_16x16x32_f16(af[m][0], bf[n][0], acc[m][n], 0,0,0);
        acc[m][n] = __builtin_amdgcn_mfma_f32_16x16x32_f16(af[m][1], bf[n][1], acc[m][n], 0,0,0);
      }
    __builtin_amdgcn_s_setprio(0);
    __builtin_amdgcn_s_barrier();
    // ---------------- phase 1
#pragma unroll
    for (int n = 2; n < 4; n++){
      bf[n][0] = *(const f16x8*)&Bs[d][1][((n-2)*64 + brow)*64 + cbo0];
      bf[n][1] = *(const f16x8*)&Bs[d][1][((n-2)*64 + brow)*64 + cbo1];
    }
    if (st) STAGE_B(e,1,t+1);
    __builtin_amdgcn_s_barrier();
    asm volatile("s_waitcnt lgkmcnt(0)" ::: "memory");
    __builtin_amdgcn_sched_barrier(0);
    __builtin_amdgcn_s_setprio(1);
#pragma unroll
    for (int m = 0; m < 4; m++)
#pragma unroll
      for (int n = 2; n < 4; n++){
        acc[m][n] = __builtin_amdgcn_mfma_f32_16x16x32_f16(af[m][0], bf[n][0], acc[m][n], 0,0,0);
        acc[m][n] = __builtin_amdgcn_mfma_f32_16x16x32_f16(af[m][1], bf[n][1], acc[m][n], 0,0,0);
      }
    __builtin_amdgcn_s_setprio(0);
    __builtin_amdgcn_s_barrier();
    // ---------------- phase 2 (af regs reused for mhalf1)
#pragma unroll
    for (int m = 0; m < 4; m++){
      af[m][0] = *(const f16x8*)&As[d][1][(m*32 + arow)*64 + cbo0];
      af[m][1] = *(const f16x8*)&As[d][1][(m*32 + arow)*64 + cbo1];
    }
    if (st) STAGE_A(e,1,t+1);
    __builtin_amdgcn_s_barrier();
    asm volatile("s_waitcnt lgkmcnt(0)" ::: "memory");
    __builtin_amdgcn_sched_barrier(0);
    __builtin_amdgcn_s_setprio(1);
#pragma unroll
    for (int m = 0; m < 4; m++)
#pragma unroll
      for (int n = 0; n < 2; n++){
        acc[4+m][n] = __builtin_amdgcn_mfma_f32_16x16x32_f16(af[m][0], bf[n][0], acc[4+m][n], 0,0,0);
        acc[4+m][n] = __builtin_amdgcn_mfma_f32_16x16x32_f16(af[m][1], bf[n][1], acc[4+m][n], 0,0,0);
      }
    __builtin_amdgcn_s_setprio(0);
    __builtin_amdgcn_s_barrier();
    // ---------------- phase 3
    if (st) asm volatile("s_waitcnt vmcnt(4)" ::: "memory");
    __builtin_amdgcn_s_setprio(1);
#pragma unroll
    for (int m = 0; m < 4; m++)
#pragma unroll
      for (int n = 2; n < 4; n++){
        acc[4+m][n] = __builtin_amdgcn_mfma_f32_16x16x32_f16(af[m][0], bf[n][0], acc[4+m][n], 0,0,0);
        acc[4+m][n] = __builtin_amdgcn_mfma_f32_16x16x32_f16(af[m][1], bf[n][1], acc[4+m][n], 0,0,0);
      }
    __builtin_amdgcn_s_setprio(0);
    __builtin_amdgcn_s_barrier();
  }
#undef STAGE_A
#undef STAGE_B

  // epilogue: C row = bm*256 + m*32 + wr*16 + (lane>>4)*4 + r; col = bn*256 + n*64 + wc*16 + (lane&15)
  const int cc = l15;
  const int rr = lhi * 4;
#pragma unroll
  for (int m = 0; m < 8; m++){
#pragma unroll
    for (int n = 0; n < 4; n++){
      const int col = bn * 256 + n * 64 + wc * 16 + cc;
#pragma unroll
      for (int r = 0; r < 4; r++){
        const int row = bm * 256 + m * 32 + wr * 16 + rr + r;
        float v = acc[m][n][r];
        if constexpr (MODE == 0){
          if (bias0) v += bias0[col];
          Cf[(long)bz * bsC + (long)row * ldc + col] = v;
        } else {  // MODE 4
          if (col < 2048){
            v += (col < 1024) ? bias0[col] : bias1[col - 1024];
            Ch[(long)row * ldc + col] = (f16)v;
          } else {
            v += bias2[col - 2048];
            const int b2 = row >> 11, tt = row & 2047;
            vT[(long)b2 * DIM * SEQ + (long)(col - 2048) * SEQ + tt] = (f16)v;
          }
        }
      }
    }
  }
}

// ---------------------------------------------------------------------------
// m97-style 128x128 GEMM kept for PV and Wo (grids too small for 256^2).
// MODE 0: fp32 out (+bias0), MODE 2: fp16 out (+bias0)
// ---------------------------------------------------------------------------
template<int MODE>
__global__ __launch_bounds__(256, 2)
void gemm_bt(const f16* __restrict__ A, const f16* __restrict__ B,
             int K, int lda, int ldb, long bsA, long bsB, long bsC,
             float* __restrict__ Cf, f16* __restrict__ Ch,
             const float* __restrict__ bias0, int ldc)
{
  __shared__ __align__(16) f16 As[128 * 32];
  __shared__ __align__(16) f16 Bs[128 * 32];
  const int tid  = threadIdx.x;
  const int lane = tid & 63;
  const int wid  = tid >> 6;
  const int bm = blockIdx.x, bn = blockIdx.y, bz = blockIdx.z;

  f32x4 acc[4][4];
#pragma unroll
  for (int i = 0; i < 4; i++)
#pragma unroll
    for (int j = 0; j < 4; j++) acc[i][j] = (f32x4){0.f, 0.f, 0.f, 0.f};

  const int srow = tid >> 2;
  const int scol = (tid & 3) * 8;
  const int wrow = (wid >> 1) * 64;
  const int wcol = (wid & 1) * 64;
  const int lrow = lane & 15;
  const int lko  = (lane >> 4) * 8;

  const f16* Ag = A + (long)bz * bsA + (long)(bm * 128 + srow) * lda + scol;
  const f16* Bg = B + (long)bz * bsB + (long)(bn * 128 + srow) * ldb + scol;

  for (int k0 = 0; k0 < K; k0 += 32){
    __syncthreads();
    const f16* ga = Ag + k0;
    const f16* gb = Bg + k0;
    GLOAD16(ga, &As[tid * 8]);
    GLOAD16(ga + (long)64 * lda, &As[2048 + tid * 8]);
    GLOAD16(gb, &Bs[tid * 8]);
    GLOAD16(gb + (long)64 * ldb, &Bs[2048 + tid * 8]);
    __syncthreads();
    f16x8 af[4], bfr[4];
#pragma unroll
    for (int i = 0; i < 4; i++)
      af[i] = *(const f16x8*)&As[(wrow + i * 16 + lrow) * 32 + lko];
#pragma unroll
    for (int j = 0; j < 4; j++)
      bfr[j] = *(const f16x8*)&Bs[(wcol + j * 16 + lrow) * 32 + lko];
#pragma unroll
    for (int i = 0; i < 4; i++)
#pragma unroll
      for (int j = 0; j < 4; j++)
        acc[i][j] = __builtin_amdgcn_mfma_f32_16x16x32_f16(af[i], bfr[j], acc[i][j], 0, 0, 0);
  }

  const int cc = lane & 15;
  const int rr = (lane >> 4) * 4;
#pragma unroll
  for (int i = 0; i < 4; i++){
#pragma unroll
    for (int j = 0; j < 4; j++){
      const int col = bn * 128 + wcol + j * 16 + cc;
#pragma unroll
      for (int r = 0; r < 4; r++){
        const int row = bm * 128 + wrow + i * 16 + rr + r;
        float v = acc[i][j][r];
        if (bias0) v += bias0[col];
        if constexpr (MODE == 0){
          Cf[(long)bz * bsC + (long)row * ldc + col] = v;
        } else {
          Ch[(long)bz * bsC + (long)row * ldc + col] = (f16)v;
        }
      }
    }
  }
}

// One block per row: theta(qk) -> softmax -> fp16 attn. Row of 2048 in regs.
__global__ __launch_bounds__(256)
void softmax_kernel(const float* __restrict__ qk, f16* __restrict__ attn){
  const long row = blockIdx.x;
  const float* src = qk + row * SEQ;
  f16* dst = attn + row * SEQ;
  const int tid = threadIdx.x;
  float th[8];
  float mx = -1e30f;
#pragma unroll
  for (int j = 0; j < 8; j++){
    float x = src[tid + j * 256];
    float sg = 1.f / (1.f + __expf(-x));
    float t = 0.5f + 0.2f * sg + 0.15f * tanhf(x) + 0.1f * fmaxf(x, 0.f);
    th[j] = t;
    mx = fmaxf(mx, t);
  }
#pragma unroll
  for (int o = 32; o > 0; o >>= 1) mx = fmaxf(mx, __shfl_xor(mx, o, 64));
  __shared__ float redm[4], reds[4];
  const int wv = tid >> 6;
  if ((tid & 63) == 0) redm[wv] = mx;
  __syncthreads();
  mx = fmaxf(fmaxf(redm[0], redm[1]), fmaxf(redm[2], redm[3]));
  float p[8]; float sum = 0.f;
#pragma unroll
  for (int j = 0; j < 8; j++){ p[j] = __expf(th[j] - mx); sum += p[j]; }
#pragma unroll
  for (int o = 32; o > 0; o >>= 1) sum += __shfl_xor(sum, o, 64);
  if ((tid & 63) == 0) reds[wv] = sum;
  __syncthreads();
  sum = reds[0] + reds[1] + reds[2] + reds[3];
  const float inv = 1.f / sum;
#pragma unroll
  for (int j = 0; j < 8; j++) dst[tid + j * 256] = (f16)(p[j] * inv);
}

extern "C" void kernel_launch(void* const* d_in, const int* in_sizes, int n_in,
                              void* d_out, int out_size, void* d_ws, size_t ws_size,
                              hipStream_t stream){
  const float* x  = (const float*)d_in[0];
  const float* Wq = (const float*)d_in[1];
  const float* bq = (const float*)d_in[2];
  const float* Wk = (const float*)d_in[3];
  const float* bk = (const float*)d_in[4];
  const float* Wv = (const float*)d_in[5];
  const float* bv = (const float*)d_in[6];
  const float* Wo = (const float*)d_in[7];
  const float* bo = (const float*)d_in[8];
  float* out = (float*)d_out;

  char* ws = (char*)d_ws;
  size_t off = 0;
  auto alloc = [&](size_t bytes) -> char* {
    char* p = ws + off; off += (bytes + 255) & ~(size_t)255; return p;
  };

  float* qkbuf = (float*)alloc(sizeof(float) * (size_t)NBATCH * SEQ * SEQ);  // 33.5 MB
  f16* x16   = (f16*)alloc(2ull * MTOT * DIM);          // 8 MB
  f16* Wcat  = (f16*)alloc(2ull * 3 * DIM * DIM);       // 6 MB  [Wq;Wk;Wv]
  f16* Wo16  = (f16*)alloc(2ull * DIM * DIM);           // 2 MB
  f16* qkcat = (f16*)alloc(2ull * MTOT * 2 * DIM);      // 16 MB [q|k] per row
  f16* vT    = (f16*)alloc(2ull * NBATCH * DIM * SEQ);  // 8 MB  [b][d][t]
  f16* attn  = (f16*)alloc(2ull * NBATCH * SEQ * SEQ);  // 16 MB
  f16* outb  = (f16*)alloc(2ull * MTOT * DIM);          // 8 MB

  if (off > ws_size){
    fill_kernel<<<(out_size + 255) / 256, 256, 0, stream>>>(out, 12345.0f, out_size);
    return;
  }

  cvt_x_kernel<<<MTOT * DIM / 4 / 256, 256, 0, stream>>>(x, x16);
  cvt_w_kernel<<<4 * DIM * DIM / 4 / 256, 256, 0, stream>>>(Wq, Wk, Wv, Wo, Wcat, Wo16);

  // fused [q|k|vT] = x @ [Wq;Wk;Wv]^T + bias  (8-phase 256^2; grid 16x12 = 192 blocks)
  gemm8p<4><<<dim3(MTOT / 256, 3 * DIM / 256, 1), 512, 0, stream>>>(
      x16, Wcat, DIM, DIM, DIM, 0, 0, 0,
      nullptr, qkcat, vT, bq, bk, bv, 2 * DIM);

  // qk = q @ k^T per batch, fp32 out  (8-phase 256^2; grid 8x8x2 = 128 blocks)
  gemm8p<0><<<dim3(SEQ / 256, SEQ / 256, NBATCH), 512, 0, stream>>>(
      qkcat, qkcat + DIM, DIM, 2 * DIM, 2 * DIM,
      (long)SEQ * 2 * DIM, (long)SEQ * 2 * DIM, (long)SEQ * SEQ,
      qkbuf, nullptr, nullptr, nullptr, nullptr, nullptr, SEQ);

  // theta + softmax -> fp16 attn
  softmax_kernel<<<NBATCH * SEQ, 256, 0, stream>>>(qkbuf, attn);

  // out = attn @ v  (m97 128^2; grid 16x8x2 = 256 blocks)
  gemm_bt<2><<<dim3(SEQ / 128, DIM / 128, NBATCH), 256, 0, stream>>>(
      attn, vT, SEQ, SEQ, SEQ,
      (long)SEQ * SEQ, (long)DIM * SEQ, (long)SEQ * DIM,
      nullptr, outb, nullptr, DIM);

  // y = out @ Wo^T + bo, fp32 to d_out  (m97 128^2; grid 32x8)
  gemm_bt<0><<<dim3(MTOT / 128, DIM / 128, 1), 256, 0, stream>>>(
      outb, Wo16, DIM, DIM, DIM, 0, 0, 0,
      out, nullptr, bo, DIM);
}

// Round 4
// 169.403 us; speedup vs baseline: 1.1653x; 1.1653x over previous
//
#include <hip/hip_runtime.h>
#include <hip/hip_fp16.h>
#include <stdint.h>

typedef _Float16 f16;
typedef __attribute__((ext_vector_type(8))) _Float16 f16x8;
typedef __attribute__((ext_vector_type(4))) _Float16 f16x4;
typedef __attribute__((ext_vector_type(4))) float f32x4;

#define SEQ 2048
#define DIM 1024
#define NBATCH 2
#define MTOT 4096  // NBATCH*SEQ

__global__ void fill_kernel(float* p, float v, int n){
  int i = blockIdx.x * 256 + threadIdx.x;
  if (i < n) p[i] = v;
}

// Merged fp32->fp16 convert: blocks 0..4095 -> x (4M), 4096..8191 -> weights.
__global__ void cvt_all(const float* __restrict__ x, const float* __restrict__ Wq,
                        const float* __restrict__ Wk, const float* __restrict__ Wv,
                        const float* __restrict__ Wo,
                        f16* __restrict__ x16, f16* __restrict__ Wcat, f16* __restrict__ Wo16){
  int b = blockIdx.x;
  const float* src; f16* dst; int i;
  if (b < 4096){
    src = x; dst = x16; i = b * 256 + threadIdx.x;
  } else {
    int t = (b - 4096) >> 10;
    i = ((b - 4096) & 1023) * 256 + threadIdx.x;
    src = t == 0 ? Wq : t == 1 ? Wk : t == 2 ? Wv : Wo;
    dst = (t == 3) ? Wo16 : Wcat + (size_t)t * DIM * DIM;
  }
  float4 v = ((const float4*)src)[i];
  ((f16x4*)dst)[i] = (f16x4){(f16)v.x, (f16)v.y, (f16)v.z, (f16)v.w};
}

#define GLOAD16(SRC, DST) __builtin_amdgcn_global_load_lds( \
    (__attribute__((address_space(1))) void*)(SRC), \
    (__attribute__((address_space(3))) void*)(DST), 16, 0, 0)

// ---------------------------------------------------------------------------
// 128x128 GEMM, BK=64, double-buffered LDS, ONE barrier per K-step (T3-min):
//   iter t: issue 8 global_load_lds for tile t+1 into buf e, THEN ds_read +
//   32 MFMA from buf d, then __syncthreads() (its vmcnt(0)+lgkmcnt(0) drain is
//   exactly the required "stage landed / reads done" condition).
// LDS 64 KiB -> 2 blocks/CU. XOR swizzle: LDS[r][cb] = G[r][cb ^ (r&7)]
// (pre-swizzled global source + linear gload_lds dest; reads apply same XOR;
//  measured 0 bank conflicts in R3 with this mapping).
// C = A @ B^T. MODEs:
//   0: fp32 out (+bias0)                          -> Cf
//   2: fp16 out scaled by scale[bz*SEQ+row]       -> Ch   (PV)
//   4: fused qkv: col<2048 -> Ch(q|k), col>=2048 -> vT[b][d][t]
//   5: theta+exp epilogue: P = exp(min(theta-10,11)) fp16 -> Ch  (qk)
// ---------------------------------------------------------------------------
template<int MODE>
__global__ __launch_bounds__(256, 2)
void gemm2p(const f16* __restrict__ A, const f16* __restrict__ B,
            int K, int lda, int ldb, long bsA, long bsB, long bsC,
            float* __restrict__ Cf, f16* __restrict__ Ch, f16* __restrict__ vT,
            const float* __restrict__ bias0, const float* __restrict__ bias1,
            const float* __restrict__ bias2, const float* __restrict__ scale,
            int ldc)
{
  __shared__ __align__(16) f16 As[2][8192];
  __shared__ __align__(16) f16 Bs[2][8192];
  const int tid  = threadIdx.x;
  const int lane = tid & 63;
  const int wid  = tid >> 6;
  const int bm = blockIdx.x, bn = blockIdx.y, bz = blockIdx.z;

  // staging map: load l covers rows l*32+(tid>>3), swizzled colblk (tid&7)^(r&7)
  const int s_r  = tid >> 3;            // 0..31
  const int s_cb = (tid & 7) ^ (s_r & 7);
  const f16* Abase = A + (long)bz * bsA + (long)(bm * 128 + s_r) * lda + s_cb * 8;
  const f16* Bbase = B + (long)bz * bsB + (long)(bn * 128 + s_r) * ldb + s_cb * 8;

#define STG(E, T) do{ \
    GLOAD16(Abase + (long)(T)*64,                  &As[E][       tid*8]); \
    GLOAD16(Abase + (long)(T)*64 + (long)32 * lda, &As[E][2048 + tid*8]); \
    GLOAD16(Abase + (long)(T)*64 + (long)64 * lda, &As[E][4096 + tid*8]); \
    GLOAD16(Abase + (long)(T)*64 + (long)96 * lda, &As[E][6144 + tid*8]); \
    GLOAD16(Bbase + (long)(T)*64,                  &Bs[E][       tid*8]); \
    GLOAD16(Bbase + (long)(T)*64 + (long)32 * ldb, &Bs[E][2048 + tid*8]); \
    GLOAD16(Bbase + (long)(T)*64 + (long)64 * ldb, &Bs[E][4096 + tid*8]); \
    GLOAD16(Bbase + (long)(T)*64 + (long)96 * ldb, &Bs[E][6144 + tid*8]); \
  }while(0)

  // frag-read addressing
  const int l15 = lane & 15, l7 = lane & 7, lhi = lane >> 4;
  const int wrow = (wid >> 1) * 64;
  const int wcol = (wid & 1) * 64;
  const int ar = (wrow + l15) * 64;      // + i*1024
  const int br = (wcol + l15) * 64;      // + j*1024
  const int cb0 = ((0 + lhi) ^ l7) * 8;  // kk=0 (k 0..31)
  const int cb1 = ((4 + lhi) ^ l7) * 8;  // kk=1 (k 32..63)

  f32x4 acc[4][4] = {};
  const int NT = K >> 6;

  STG(0, 0);
  __syncthreads();

  for (int t = 0; t < NT; ++t){
    const int d = t & 1;
    if (t + 1 < NT) STG(d ^ 1, t + 1);   // stage next tile first (overlaps compute)
    f16x8 af[4], bf[4];
    // kk = 0
#pragma unroll
    for (int i = 0; i < 4; i++) af[i] = *(const f16x8*)&As[d][ar + i * 1024 + cb0];
#pragma unroll
    for (int j = 0; j < 4; j++) bf[j] = *(const f16x8*)&Bs[d][br + j * 1024 + cb0];
    __builtin_amdgcn_s_setprio(1);
#pragma unroll
    for (int i = 0; i < 4; i++)
#pragma unroll
      for (int j = 0; j < 4; j++)
        acc[i][j] = __builtin_amdgcn_mfma_f32_16x16x32_f16(af[i], bf[j], acc[i][j], 0, 0, 0);
    __builtin_amdgcn_s_setprio(0);
    // kk = 1
#pragma unroll
    for (int i = 0; i < 4; i++) af[i] = *(const f16x8*)&As[d][ar + i * 1024 + cb1];
#pragma unroll
    for (int j = 0; j < 4; j++) bf[j] = *(const f16x8*)&Bs[d][br + j * 1024 + cb1];
    __builtin_amdgcn_s_setprio(1);
#pragma unroll
    for (int i = 0; i < 4; i++)
#pragma unroll
      for (int j = 0; j < 4; j++)
        acc[i][j] = __builtin_amdgcn_mfma_f32_16x16x32_f16(af[i], bf[j], acc[i][j], 0, 0, 0);
    __builtin_amdgcn_s_setprio(0);
    __syncthreads();   // drains vmcnt (stage landed) + lgkm; one barrier per tile
  }
#undef STG

  // Epilogue. C/D layout: col = lane&15, row = (lane>>4)*4 + reg
  const int cc = l15;
  const int rr = lhi * 4;
#pragma unroll
  for (int i = 0; i < 4; i++){
#pragma unroll
    for (int j = 0; j < 4; j++){
      const int col = bn * 128 + wcol + j * 16 + cc;
#pragma unroll
      for (int r = 0; r < 4; r++){
        const int row = bm * 128 + wrow + i * 16 + rr + r;
        float v = acc[i][j][r];
        if constexpr (MODE == 0){
          if (bias0) v += bias0[col];
          Cf[(long)bz * bsC + (long)row * ldc + col] = v;
        } else if constexpr (MODE == 2){
          v *= scale[bz * SEQ + row];
          Ch[(long)bz * bsC + (long)row * ldc + col] = (f16)v;
        } else if constexpr (MODE == 4){
          if (col < 2048){
            v += (col < 1024) ? bias0[col] : bias1[col - 1024];
            Ch[(long)row * ldc + col] = (f16)v;
          } else {
            v += bias2[col - 2048];
            const int b2 = row >> 11, tt = row & 2047;
            vT[(long)b2 * DIM * SEQ + (long)(col - 2048) * SEQ + tt] = (f16)v;
          }
        } else {  // MODE 5: theta + unnormalized exp (shift 10, clamp 11)
          const float e1 = __expf(-v);          // x<<0 -> inf -> sg=0, th=-1 (correct limits)
          const float sg = 1.f / (1.f + e1);
          const float e2 = e1 * e1;             // e^{-2x}
          const float th = 2.f / (1.f + e2) - 1.f;
          const float theta = 0.5f + 0.2f * sg + 0.15f * th + 0.1f * fmaxf(v, 0.f);
          const float P = __expf(fminf(theta - 10.f, 11.f));
          Ch[(long)bz * bsC + (long)row * ldc + col] = (f16)P;
        }
      }
    }
  }
}

// One block per row: inv_rowsum of fp16 P (2048 elems = 256 thr x f16x8)
__global__ __launch_bounds__(256)
void rowsum_kernel(const f16* __restrict__ P, float* __restrict__ inv){
  const long row = blockIdx.x;
  const int tid = threadIdx.x;
  f16x8 v = ((const f16x8*)(P + row * SEQ))[tid];
  float s = 0.f;
#pragma unroll
  for (int j = 0; j < 8; j++) s += (float)v[j];
#pragma unroll
  for (int o = 32; o > 0; o >>= 1) s += __shfl_xor(s, o, 64);
  __shared__ float red[4];
  if ((tid & 63) == 0) red[tid >> 6] = s;
  __syncthreads();
  if (tid == 0) inv[row] = 1.f / (red[0] + red[1] + red[2] + red[3]);
}

extern "C" void kernel_launch(void* const* d_in, const int* in_sizes, int n_in,
                              void* d_out, int out_size, void* d_ws, size_t ws_size,
                              hipStream_t stream){
  const float* x  = (const float*)d_in[0];
  const float* Wq = (const float*)d_in[1];
  const float* bq = (const float*)d_in[2];
  const float* Wk = (const float*)d_in[3];
  const float* bk = (const float*)d_in[4];
  const float* Wv = (const float*)d_in[5];
  const float* bv = (const float*)d_in[6];
  const float* Wo = (const float*)d_in[7];
  const float* bo = (const float*)d_in[8];
  float* out = (float*)d_out;

  char* ws = (char*)d_ws;
  size_t off = 0;
  auto alloc = [&](size_t bytes) -> char* {
    char* p = ws + off; off += (bytes + 255) & ~(size_t)255; return p;
  };

  f16* x16   = (f16*)alloc(2ull * MTOT * DIM);          // 8 MB
  f16* Wcat  = (f16*)alloc(2ull * 3 * DIM * DIM);       // 6 MB  [Wq;Wk;Wv]
  f16* Wo16  = (f16*)alloc(2ull * DIM * DIM);           // 2 MB
  f16* qkcat = (f16*)alloc(2ull * MTOT * 2 * DIM);      // 16 MB [q|k] per row
  f16* vT    = (f16*)alloc(2ull * NBATCH * DIM * SEQ);  // 8 MB  [b][d][t]
  f16* Pbuf  = (f16*)alloc(2ull * NBATCH * SEQ * SEQ);  // 16 MB unnormalized exp
  f16* outb  = (f16*)alloc(2ull * MTOT * DIM);          // 8 MB
  float* inv = (float*)alloc(4ull * MTOT);              // 16 KB

  if (off > ws_size){
    fill_kernel<<<(out_size + 255) / 256, 256, 0, stream>>>(out, 12345.0f, out_size);
    return;
  }

  cvt_all<<<8192, 256, 0, stream>>>(x, Wq, Wk, Wv, Wo, x16, Wcat, Wo16);

  // fused [q|k|vT] = x @ [Wq;Wk;Wv]^T + bias   (grid 32x24 = 768 blocks)
  gemm2p<4><<<dim3(MTOT / 128, 3 * DIM / 128, 1), 256, 0, stream>>>(
      x16, Wcat, DIM, DIM, DIM, 0, 0, 0,
      nullptr, qkcat, vT, bq, bk, bv, nullptr, 2 * DIM);

  // P = exp(theta(q@k^T) - 10) per batch, fp16  (grid 16x16x2 = 512 blocks)
  gemm2p<5><<<dim3(SEQ / 128, SEQ / 128, NBATCH), 256, 0, stream>>>(
      qkcat, qkcat + DIM, DIM, 2 * DIM, 2 * DIM,
      (long)SEQ * 2 * DIM, (long)SEQ * 2 * DIM, (long)SEQ * SEQ,
      nullptr, Pbuf, nullptr, nullptr, nullptr, nullptr, nullptr, SEQ);

  // inv row sums of P
  rowsum_kernel<<<MTOT, 256, 0, stream>>>(Pbuf, inv);

  // out = (P @ v) * inv[row]  (grid 16x8x2 = 256 blocks)
  gemm2p<2><<<dim3(SEQ / 128, DIM / 128, NBATCH), 256, 0, stream>>>(
      Pbuf, vT, SEQ, SEQ, SEQ,
      (long)SEQ * SEQ, (long)DIM * SEQ, (long)SEQ * DIM,
      nullptr, outb, nullptr, nullptr, nullptr, nullptr, inv, DIM);

  // y = out @ Wo^T + bo, fp32 to d_out  (grid 32x8)
  gemm2p<0><<<dim3(MTOT / 128, DIM / 128, 1), 256, 0, stream>>>(
      outb, Wo16, DIM, DIM, DIM, 0, 0, 0,
      out, nullptr, nullptr, bo, nullptr, nullptr, nullptr, DIM);
}

// Round 5
// 139.192 us; speedup vs baseline: 1.4182x; 1.2170x over previous
//
#include <hip/hip_runtime.h>
#include <hip/hip_fp16.h>
#include <stdint.h>

typedef _Float16 f16;
typedef __attribute__((ext_vector_type(8))) _Float16 f16x8;
typedef __attribute__((ext_vector_type(4))) _Float16 f16x4;
typedef __attribute__((ext_vector_type(4))) float f32x4;

#define SEQ 2048
#define DIM 1024
#define NBATCH 2
#define MTOT 4096  // NBATCH*SEQ

__global__ void fill_kernel(float* p, float v, int n){
  int i = blockIdx.x * 256 + threadIdx.x;
  if (i < n) p[i] = v;
}

// Merged fp32->fp16 convert + sums zero-init.
// blocks 0..4095 -> x, 4096..8191 -> weights, 8192 -> zero rowacc.
__global__ void cvt_all(const float* __restrict__ x, const float* __restrict__ Wq,
                        const float* __restrict__ Wk, const float* __restrict__ Wv,
                        const float* __restrict__ Wo,
                        f16* __restrict__ x16, f16* __restrict__ Wcat, f16* __restrict__ Wo16,
                        float* __restrict__ rowacc){
  int b = blockIdx.x;
  if (b == 8192){
    float4 z = {0.f, 0.f, 0.f, 0.f};
#pragma unroll
    for (int i = 0; i < 4; i++) ((float4*)rowacc)[threadIdx.x + i * 256] = z;
    return;
  }
  const float* src; f16* dst; int i;
  if (b < 4096){
    src = x; dst = x16; i = b * 256 + threadIdx.x;
  } else {
    int t = (b - 4096) >> 10;
    i = ((b - 4096) & 1023) * 256 + threadIdx.x;
    src = t == 0 ? Wq : t == 1 ? Wk : t == 2 ? Wv : Wo;
    dst = (t == 3) ? Wo16 : Wcat + (size_t)t * DIM * DIM;
  }
  float4 v = ((const float4*)src)[i];
  ((f16x4*)dst)[i] = (f16x4){(f16)v.x, (f16)v.y, (f16)v.z, (f16)v.w};
}

#define GLOAD16(SRC, DST) __builtin_amdgcn_global_load_lds( \
    (__attribute__((address_space(1))) void*)(SRC), \
    (__attribute__((address_space(3))) void*)(DST), 16, 0, 0)

// ---------------------------------------------------------------------------
// 128x128 GEMM, BK=64, SINGLE-buffered LDS (32 KiB -> high residency),
// 2 barriers per K-tile (16 drains at K=1024 vs 32 in the BK=32 version):
//   tile t: bar(a: prev reads done) ; STG(t) ; bar(b: drains vmcnt -> landed) ;
//           ds_read + 32 MFMA.
// XOR swizzle (verified 0 conflicts R3/R4): LDS[r][cb] = G[r][cb ^ (r&7)],
// linear gload_lds dest + pre-swizzled global source; reads apply same XOR.
// C = A @ B^T. MODEs:
//   0: fp32 out (+bias0)                                -> Cf
//   2: fp16 out scaled by 1/rowacc[bz*SEQ+row]          -> Ch   (PV)
//   4: fused qkv: col<2048 -> Ch(q|k), col>=2048 -> vT[b][d][t] (f16x4 packed)
//   5: P = exp(min(theta-10,11)) fp16 -> Ch; fused row-sum atomicAdd -> rowacc
// ---------------------------------------------------------------------------
template<int MODE>
__global__ __launch_bounds__(256, 2)
void gemm_k64(const f16* __restrict__ A, const f16* __restrict__ B,
              int K, int lda, int ldb, long bsA, long bsB, long bsC,
              float* __restrict__ Cf, f16* __restrict__ Ch, f16* __restrict__ vT,
              const float* __restrict__ bias0, const float* __restrict__ bias1,
              const float* __restrict__ bias2, float* __restrict__ rowacc,
              int ldc)
{
  __shared__ __align__(16) f16 As[8192];   // 128 rows x 64 cols
  __shared__ __align__(16) f16 Bs[8192];
  const int tid  = threadIdx.x;
  const int lane = tid & 63;
  const int wid  = tid >> 6;
  const int bm = blockIdx.x, bn = blockIdx.y, bz = blockIdx.z;

  // staging: load l covers row l*32+(tid>>3); dest linear; source col pre-swizzled
  const int s_r  = tid >> 3;            // 0..31
  const int s_cb = (tid & 7) ^ (s_r & 7);
  const f16* Abase = A + (long)bz * bsA + (long)(bm * 128 + s_r) * lda + s_cb * 8;
  const f16* Bbase = B + (long)bz * bsB + (long)(bn * 128 + s_r) * ldb + s_cb * 8;

#define STG(T) do{ \
    GLOAD16(Abase + (long)(T)*64,                  &As[       tid*8]); \
    GLOAD16(Abase + (long)(T)*64 + (long)32 * lda, &As[2048 + tid*8]); \
    GLOAD16(Abase + (long)(T)*64 + (long)64 * lda, &As[4096 + tid*8]); \
    GLOAD16(Abase + (long)(T)*64 + (long)96 * lda, &As[6144 + tid*8]); \
    GLOAD16(Bbase + (long)(T)*64,                  &Bs[       tid*8]); \
    GLOAD16(Bbase + (long)(T)*64 + (long)32 * ldb, &Bs[2048 + tid*8]); \
    GLOAD16(Bbase + (long)(T)*64 + (long)64 * ldb, &Bs[4096 + tid*8]); \
    GLOAD16(Bbase + (long)(T)*64 + (long)96 * ldb, &Bs[6144 + tid*8]); \
  }while(0)

  // frag-read addressing (swizzled)
  const int l15 = lane & 15, l7 = lane & 7, lhi = lane >> 4;
  const int wrow = (wid >> 1) * 64;
  const int wcol = (wid & 1) * 64;
  const int ar = (wrow + l15) * 64;      // + i*1024
  const int br = (wcol + l15) * 64;      // + j*1024
  const int cb0 = ((0 + lhi) ^ l7) * 8;  // k 0..31
  const int cb1 = ((4 + lhi) ^ l7) * 8;  // k 32..63

  f32x4 acc[4][4] = {};
  const int NT = K >> 6;

  for (int t = 0; t < NT; ++t){
    __syncthreads();                     // prev tile's ds_reads done
    STG(t);
    __syncthreads();                     // staging landed (vmcnt drained)
    f16x8 af[4], bf[4];
#pragma unroll
    for (int i = 0; i < 4; i++) af[i] = *(const f16x8*)&As[ar + i * 1024 + cb0];
#pragma unroll
    for (int j = 0; j < 4; j++) bf[j] = *(const f16x8*)&Bs[br + j * 1024 + cb0];
#pragma unroll
    for (int i = 0; i < 4; i++)
#pragma unroll
      for (int j = 0; j < 4; j++)
        acc[i][j] = __builtin_amdgcn_mfma_f32_16x16x32_f16(af[i], bf[j], acc[i][j], 0, 0, 0);
#pragma unroll
    for (int i = 0; i < 4; i++) af[i] = *(const f16x8*)&As[ar + i * 1024 + cb1];
#pragma unroll
    for (int j = 0; j < 4; j++) bf[j] = *(const f16x8*)&Bs[br + j * 1024 + cb1];
#pragma unroll
    for (int i = 0; i < 4; i++)
#pragma unroll
      for (int j = 0; j < 4; j++)
        acc[i][j] = __builtin_amdgcn_mfma_f32_16x16x32_f16(af[i], bf[j], acc[i][j], 0, 0, 0);
  }
#undef STG

  // Epilogue. C/D layout: col = lane&15 (cc), row = (lane>>4)*4 + reg
  const int cc = l15;
  const int rr = lhi * 4;

  if constexpr (MODE == 0){
#pragma unroll
    for (int i = 0; i < 4; i++)
#pragma unroll
      for (int j = 0; j < 4; j++){
        const int col = bn * 128 + wcol + j * 16 + cc;
        const float badd = bias0 ? bias0[col] : 0.f;
#pragma unroll
        for (int r = 0; r < 4; r++){
          const int row = bm * 128 + wrow + i * 16 + rr + r;
          Cf[(long)bz * bsC + (long)row * ldc + col] = acc[i][j][r] + badd;
        }
      }
  } else if constexpr (MODE == 2){
#pragma unroll
    for (int i = 0; i < 4; i++)
#pragma unroll
      for (int r = 0; r < 4; r++){
        const int row = bm * 128 + wrow + i * 16 + rr + r;
        const float inv = 1.f / rowacc[bz * SEQ + row];
#pragma unroll
        for (int j = 0; j < 4; j++){
          const int col = bn * 128 + wcol + j * 16 + cc;
          Ch[(long)bz * bsC + (long)row * ldc + col] = (f16)(acc[i][j][r] * inv);
        }
      }
  } else if constexpr (MODE == 4){
#pragma unroll
    for (int i = 0; i < 4; i++)
#pragma unroll
      for (int j = 0; j < 4; j++){
        const int col = bn * 128 + wcol + j * 16 + cc;
        if (col < 2048){
          const float badd = (col < 1024) ? bias0[col] : bias1[col - 1024];
#pragma unroll
          for (int r = 0; r < 4; r++){
            const int row = bm * 128 + wrow + i * 16 + rr + r;
            Ch[(long)row * ldc + col] = (f16)(acc[i][j][r] + badd);
          }
        } else {
          const int d = col - 2048;
          const float badd = bias2[d];
          const int row0 = bm * 128 + wrow + i * 16 + rr;   // 4 consecutive rows
          const int b2 = row0 >> 11, t0 = row0 & 2047;
          f16x4 pk = {(f16)(acc[i][j][0] + badd), (f16)(acc[i][j][1] + badd),
                      (f16)(acc[i][j][2] + badd), (f16)(acc[i][j][3] + badd)};
          *(f16x4*)&vT[(long)b2 * DIM * SEQ + (long)d * SEQ + t0] = pk;
        }
      }
  } else {  // MODE 5: theta + unnormalized exp, fused row-sum
#pragma unroll
    for (int i = 0; i < 4; i++)
#pragma unroll
      for (int r = 0; r < 4; r++){
        const int row = bm * 128 + wrow + i * 16 + rr + r;
        float rs = 0.f;
#pragma unroll
        for (int j = 0; j < 4; j++){
          const int col = bn * 128 + wcol + j * 16 + cc;
          const float v = acc[i][j][r];
          const float e1 = __expf(-v);          // x->-inf: e1=inf -> sg=0, th=-1 (correct)
          const float sg = 1.f / (1.f + e1);
          const float e2 = e1 * e1;             // e^{-2x}
          const float th = 2.f / (1.f + e2) - 1.f;
          const float theta = 0.5f + 0.2f * sg + 0.15f * th + 0.1f * fmaxf(v, 0.f);
          const float P = __expf(fminf(theta - 10.f, 11.f));
          Ch[(long)bz * bsC + (long)row * ldc + col] = (f16)P;
          rs += P;
        }
        // reduce across the 16 lanes (same lhi group) holding this row's cols
        rs += __shfl_xor(rs, 1, 64);
        rs += __shfl_xor(rs, 2, 64);
        rs += __shfl_xor(rs, 4, 64);
        rs += __shfl_xor(rs, 8, 64);
        if (cc == 0) atomicAdd(&rowacc[bz * SEQ + row], rs);
      }
  }
}

extern "C" void kernel_launch(void* const* d_in, const int* in_sizes, int n_in,
                              void* d_out, int out_size, void* d_ws, size_t ws_size,
                              hipStream_t stream){
  const float* x  = (const float*)d_in[0];
  const float* Wq = (const float*)d_in[1];
  const float* bq = (const float*)d_in[2];
  const float* Wk = (const float*)d_in[3];
  const float* bk = (const float*)d_in[4];
  const float* Wv = (const float*)d_in[5];
  const float* bv = (const float*)d_in[6];
  const float* Wo = (const float*)d_in[7];
  const float* bo = (const float*)d_in[8];
  float* out = (float*)d_out;

  char* ws = (char*)d_ws;
  size_t off = 0;
  auto alloc = [&](size_t bytes) -> char* {
    char* p = ws + off; off += (bytes + 255) & ~(size_t)255; return p;
  };

  f16* x16     = (f16*)alloc(2ull * MTOT * DIM);          // 8 MB
  f16* Wcat    = (f16*)alloc(2ull * 3 * DIM * DIM);       // 6 MB  [Wq;Wk;Wv]
  f16* Wo16    = (f16*)alloc(2ull * DIM * DIM);           // 2 MB
  f16* qkcat   = (f16*)alloc(2ull * MTOT * 2 * DIM);      // 16 MB [q|k] per row
  f16* vT      = (f16*)alloc(2ull * NBATCH * DIM * SEQ);  // 8 MB  [b][d][t]
  f16* Pbuf    = (f16*)alloc(2ull * NBATCH * SEQ * SEQ);  // 16 MB unnormalized exp
  f16* outb    = (f16*)alloc(2ull * MTOT * DIM);          // 8 MB
  float* rowac = (float*)alloc(4ull * MTOT);              // 16 KB row sums

  if (off > ws_size){
    fill_kernel<<<(out_size + 255) / 256, 256, 0, stream>>>(out, 12345.0f, out_size);
    return;
  }

  cvt_all<<<8193, 256, 0, stream>>>(x, Wq, Wk, Wv, Wo, x16, Wcat, Wo16, rowac);

  // fused [q|k|vT] = x @ [Wq;Wk;Wv]^T + bias   (grid 32x24 = 768 blocks, NT=16)
  gemm_k64<4><<<dim3(MTOT / 128, 3 * DIM / 128, 1), 256, 0, stream>>>(
      x16, Wcat, DIM, DIM, DIM, 0, 0, 0,
      nullptr, qkcat, vT, bq, bk, bv, nullptr, 2 * DIM);

  // P = exp(theta(q@k^T) - 10) fp16 + fused row sums  (grid 16x16x2, NT=16)
  gemm_k64<5><<<dim3(SEQ / 128, SEQ / 128, NBATCH), 256, 0, stream>>>(
      qkcat, qkcat + DIM, DIM, 2 * DIM, 2 * DIM,
      (long)SEQ * 2 * DIM, (long)SEQ * 2 * DIM, (long)SEQ * SEQ,
      nullptr, Pbuf, nullptr, nullptr, nullptr, nullptr, rowac, SEQ);

  // out = (P @ v) / rowsum  (grid 16x8x2, NT=32)
  gemm_k64<2><<<dim3(SEQ / 128, DIM / 128, NBATCH), 256, 0, stream>>>(
      Pbuf, vT, SEQ, SEQ, SEQ,
      (long)SEQ * SEQ, (long)DIM * SEQ, (long)SEQ * DIM,
      nullptr, outb, nullptr, nullptr, nullptr, nullptr, rowac, DIM);

  // y = out @ Wo^T + bo, fp32 to d_out  (grid 32x8, NT=16)
  gemm_k64<0><<<dim3(MTOT / 128, DIM / 128, 1), 256, 0, stream>>>(
      outb, Wo16, DIM, DIM, DIM, 0, 0, 0,
      out, nullptr, nullptr, bo, nullptr, nullptr, nullptr, DIM);
}